// Round 15
// baseline (219.435 us; speedup 1.0000x reference)
//
#include <hip/hip_runtime.h>

typedef unsigned short ushort_t;
typedef unsigned char uchar_t;
typedef __bf16 bf16x8 __attribute__((ext_vector_type(8)));
typedef float f32x4 __attribute__((ext_vector_type(4)));

__device__ __forceinline__ ushort_t f2bf(float f) {
  unsigned u = __float_as_uint(f);
  u += 0x7fff + ((u >> 16) & 1);
  return (ushort_t)(u >> 16);
}

__device__ __forceinline__ void gload16(const void* g, void* l) {
  __builtin_amdgcn_global_load_lds(
      (const __attribute__((address_space(1))) unsigned int*)g,
      (__attribute__((address_space(3))) unsigned int*)l, 16, 0, 0);
}

// ---------------- weight fp32 -> bf16, pack qk bias, zero stats2 ----------------
__global__ __launch_bounds__(256) void cvt_weights(
    const float* __restrict__ wq, const float* __restrict__ wk,
    const float* __restrict__ wv, const float* __restrict__ wo,
    const float* __restrict__ bq, const float* __restrict__ bk,
    ushort_t* __restrict__ dst, float* __restrict__ qkbias,
    float* __restrict__ stats2) {
  int b = blockIdx.x, t = threadIdx.x;
  if (b < 1024) {
    int i = b * 256 + t;
    dst[i]          = f2bf(wq[i]);
    dst[262144 + i] = f2bf(wk[i]);
    dst[524288 + i] = f2bf(wv[i]);
    dst[786432 + i] = f2bf(wo[i]);
  } else if (b < 1028) {
    int j = (b - 1024) * 256 + t;  // 0..1023
    qkbias[j] = (j < 512) ? bq[j] : bk[j - 512];
  } else {
    if (t < 128) stats2[t] = 0.f;
  }
}

// ---------------- rowsum partial reduce: l[bz][m] = sum_bx part[bz][bx][m] ----
__global__ __launch_bounds__(256) void rowsum_reduce(
    const float* __restrict__ part, float* __restrict__ l) {
  int i = blockIdx.x * 256 + threadIdx.x;   // 0..8191
  int bz = i >> 12, m = i & 4095;
  const float* p = part + (size_t)bz * 32 * 4096 + m;
  float s = 0.f;
#pragma unroll
  for (int bx = 0; bx < 32; bx++) s += p[(size_t)bx * 4096];
  l[i] = s;
}

// ---------------- group norm partial stats: 4 blocks per (b,g) ----------------
__global__ __launch_bounds__(256) void gn_stats_partial(const float* __restrict__ x,
                                                        float* __restrict__ stats2) {
  int bg = blockIdx.x >> 2, q = blockIdx.x & 3;
  const float4* p = (const float4*)(x + (size_t)bg * 65536 + q * 16384);
  float s = 0.f, ss = 0.f;
  for (int i = threadIdx.x; i < 4096; i += 256) {
    float4 v = p[i];
    s += v.x + v.y + v.z + v.w;
    ss += v.x * v.x + v.y * v.y + v.z * v.z + v.w * v.w;
  }
  for (int off = 32; off; off >>= 1) {
    s += __shfl_xor(s, off, 64);
    ss += __shfl_xor(ss, off, 64);
  }
  __shared__ float sh[8];
  int wave = threadIdx.x >> 6, lane = threadIdx.x & 63;
  if (lane == 0) { sh[wave] = s; sh[4 + wave] = ss; }
  __syncthreads();
  if (threadIdx.x == 0) {
    atomicAdd(&stats2[bg * 2], sh[0] + sh[1] + sh[2] + sh[3]);
    atomicAdd(&stats2[bg * 2 + 1], sh[4] + sh[5] + sh[6] + sh[7]);
  }
}

__global__ __launch_bounds__(64) void gn_finalize(const float* __restrict__ stats2,
                                                  float* __restrict__ stats) {
  int t = threadIdx.x;  // 64 groups total (2 batches x 32)
  float s = stats2[t * 2], ss = stats2[t * 2 + 1];
  float mean = s * (1.f / 65536.f);
  float var = ss * (1.f / 65536.f) - mean * mean;
  stats[t * 2] = mean;
  stats[t * 2 + 1] = rsqrtf(var + 1e-6f);
}

// ---------------- GN apply + transpose: x (b,c,n) -> hnT (b,n,c) bf16 ----------------
__global__ __launch_bounds__(256) void gn_apply(
    const float* __restrict__ x, const float* __restrict__ gamma,
    const float* __restrict__ beta, const float* __restrict__ stats,
    ushort_t* __restrict__ hnT) {
  __shared__ float T[32][33];
  int i0 = blockIdx.x * 32, c0 = blockIdx.y * 32, b = blockIdx.z;
  int tx = threadIdx.x, ty = threadIdx.y;  // (32,8)
#pragma unroll
  for (int k = 0; k < 4; k++) {
    int cl = ty + k * 8;
    int c = c0 + cl;
    int bg = (b * 32 + (c >> 4)) * 2;
    float mean = stats[bg], rstd = stats[bg + 1];
    float v = x[((size_t)(b * 512 + c)) * 4096 + i0 + tx];
    T[cl][tx] = (v - mean) * rstd * gamma[c] + beta[c];
  }
  __syncthreads();
#pragma unroll
  for (int k = 0; k < 4; k++) {
    int il = ty + k * 8;
    hnT[((size_t)b * 4096 + i0 + il) * 512 + c0 + tx] = f2bf(T[tx][il]);
  }
}

// ---------------- bf16 C = A * B^T GEMM, 128 x BN tile, UNR k-chunks/buffer --
// UNR=2 for the 512-wg (2 wg/CU, grid-limited) launches: halves the
// barrier+drain count (round-4: −8us across the three abt launches).
// omode: 0 = bf16 out, 1 = fp32 + residual, 2 = fp8 e4m3 out.
template <int BN, int UNR>
__global__ __launch_bounds__(256) void gemm_abt(
    const ushort_t* __restrict__ A, long long sA, int lda,
    const ushort_t* __restrict__ B, long long sB, int ldb,
    int K, int N, int ldc,
    ushort_t* __restrict__ outB, long long sC,
    const float* __restrict__ bias, int bias_mode, float scale,
    float* __restrict__ outF, const float* __restrict__ resid,
    const float* __restrict__ colscale, int swiz, int omode) {
  constexpr int CPW = (8 + BN / 16) / 4;
  constexpr int SB = (128 + BN) * 32;      // halfwords per 32-elem k-chunk
  constexpr int STEP = 32 * UNR;
  constexpr int MI = (BN == 128) ? 4 : 2;
  constexpr int NI = 4;
  __shared__ __align__(16) ushort_t Ls[2][UNR * SB];

  int bx = blockIdx.x, by = blockIdx.y, bz = blockIdx.z;
  if (swiz) {
    unsigned nx = gridDim.x, ny = gridDim.y;
    unsigned id = (blockIdx.z * ny + blockIdx.y) * nx + blockIdx.x;
    unsigned pb8 = (nx * ny) >> 3;
    unsigned c = id & 7, j = id >> 3;
    bz = j / pb8;
    unsigned jb = j - bz * pb8;
    unsigned jy = jb / nx;
    by = c * (ny >> 3) + jy;
    bx = jb - jy * nx;
  }

  int m0 = by * 128, n0 = bx * BN;
  int t = threadIdx.x;
  int lane = t & 63;
  int quad = lane >> 4, l16 = lane & 15;
  int wave = t >> 6;
  int wm = (BN == 128) ? (wave >> 1) * 64 : wave * 32;
  int wn = (BN == 128) ? (wave & 1) * 64 : 0;

  f32x4 acc[MI][NI];
#pragma unroll
  for (int i = 0; i < MI; i++)
#pragma unroll
    for (int j = 0; j < NI; j++)
#pragma unroll
      for (int r = 0; r < 4; r++) acc[i][j][r] = 0.f;

  const ushort_t* gp[CPW];
  int lofs[CPW];
  int crow = lane >> 2, skoff = (lane & 3) * 8;
#pragma unroll
  for (int i = 0; i < CPW; i++) {
    int c = wave * CPW + i;
    if (c < 8) {
      gp[i] = A + (size_t)bz * sA + (size_t)(m0 + c * 16 + crow) * lda + skoff;
      lofs[i] = c * 1024 + lane * 16;
    } else {
      int slot = (c - 8) * 16 + crow;
      int arow = (slot & ~63) + ((slot & 15) * 4) + ((slot & 63) >> 4);
      gp[i] = B + (size_t)bz * sB + (size_t)(n0 + arow) * ldb + skoff;
      lofs[i] = 8192 + (c - 8) * 1024 + lane * 16;
    }
  }
  char* lbase = (char*)&Ls[0][0];

#pragma unroll
  for (int s = 0; s < UNR; s++)
#pragma unroll
    for (int i = 0; i < CPW; i++)
      gload16(gp[i] + s * 32, lbase + s * (SB * 2) + lofs[i]);

  for (int k0 = 0; k0 < K; k0 += STEP) {
    int p = (k0 / STEP) & 1;
    __syncthreads();
    if (k0 + STEP < K) {
      int pofs = (p ^ 1) * (UNR * SB * 2);
#pragma unroll
      for (int s = 0; s < UNR; s++)
#pragma unroll
        for (int i = 0; i < CPW; i++)
          gload16(gp[i] + k0 + STEP + s * 32, lbase + pofs + s * (SB * 2) + lofs[i]);
    }
#pragma unroll
    for (int s = 0; s < UNR; s++) {
      bf16x8 af[MI], bfr[NI];
#pragma unroll
      for (int i = 0; i < MI; i++)
        af[i] = *(const bf16x8*)&Ls[p][s * SB + (wm + i * 16 + l16) * 32 + quad * 8];
#pragma unroll
      for (int j = 0; j < NI; j++)
        bfr[j] = *(const bf16x8*)&Ls[p][s * SB + 4096 + (wn + j * 16 + l16) * 32 + quad * 8];
#pragma unroll
      for (int mi = 0; mi < MI; mi++)
#pragma unroll
        for (int ni = 0; ni < NI; ni++)
          acc[mi][ni] = __builtin_amdgcn_mfma_f32_16x16x32_bf16(af[mi], bfr[ni], acc[mi][ni], 0, 0, 0);
    }
  }

  size_t cbase = (size_t)bz * sC;
  int gnb = n0 + wn + l16 * 4;
  float cs4[4] = {1.f, 1.f, 1.f, 1.f};
  if (colscale) {
    float4 c4 = *(const float4*)&colscale[(size_t)bz * N + gnb];
    cs4[0] = 1.f / c4.x; cs4[1] = 1.f / c4.y; cs4[2] = 1.f / c4.z; cs4[3] = 1.f / c4.w;
  }
  float b4[4] = {0.f, 0.f, 0.f, 0.f};
  if (bias_mode == 2) {
    float4 t4 = *(const float4*)&bias[gnb];
    b4[0] = t4.x; b4[1] = t4.y; b4[2] = t4.z; b4[3] = t4.w;
  }
#pragma unroll
  for (int mi = 0; mi < MI; mi++) {
#pragma unroll
    for (int r = 0; r < 4; r++) {
      int m = m0 + wm + mi * 16 + quad * 4 + r;
      float rbias = (bias_mode == 1) ? bias[m] : 0.f;
      float v4[4];
#pragma unroll
      for (int ni = 0; ni < NI; ni++) {
        float val = acc[mi][ni][r];
        if (colscale) val *= cs4[ni];
        val += (bias_mode == 2) ? b4[ni] : rbias;
        val *= scale;
        v4[ni] = val;
      }
      size_t idx = cbase + (size_t)m * ldc + gnb;
      if (omode == 1) {
        float4 rv = *(const float4*)&resid[idx];
        float4 ov = make_float4(v4[0] + rv.x, v4[1] + rv.y, v4[2] + rv.z, v4[3] + rv.w);
        *(float4*)&outF[idx] = ov;
      } else if (omode == 2) {
        unsigned w = __builtin_amdgcn_cvt_pk_fp8_f32(v4[0], v4[1], 0u, false);
        w = __builtin_amdgcn_cvt_pk_fp8_f32(v4[2], v4[3], w, true);
        *(unsigned*)&((uchar_t*)outB)[idx] = w;
      } else {
        unsigned lo = (unsigned)f2bf(v4[0]) | ((unsigned)f2bf(v4[1]) << 16);
        unsigned hi = (unsigned)f2bf(v4[2]) | ((unsigned)f2bf(v4[3]) << 16);
        *(uint2*)&outB[idx] = make_uint2(lo, hi);
      }
    }
  }
}

// ---------------- QK: S' = exp(scale*Q.K^T)/16 fp8 + PRIVATE rowsum ----------
// BM=256 x BN=128 tile, 8 waves, BKB=64 seg-transposed (round-14: 46.3us,
// MfmaUtil 29, the fixed-cost amortization win) + depth-2 COUNTED-vmcnt
// pipeline grafted from the refcheck-proven rounds-6/10/PV skeleton.
// Rationale: counted vmcnt was null on 4-wave QK shapes (rounds 6/10), but
// the 8-wave MH=2 shape is a different arbitration regime (24 resident
// waves, half-length serial chains, 3 wg/CU) — the last untested combo.
// Schedule/iter: vmcnt(3) [tile kt landed; kt+1 in flight] ; s_barrier ;
// setprio(1) MFMA setprio(0) ; lgkmcnt(0)+sched_barrier(0)+s_barrier ;
// stage tile kt+2 into buf[kt&1]. Tile coverage: prologue {0,1}; kt=0..5
// stage {2..7}; NT=8 exact. gload_lds counts in vmcnt only -> vmcnt(3)+
// barrier gives LDS visibility (proven skeleton semantics).
// Epilogue: LDS-only rowsum (rsum[256]) -> collision-free partial store.
__global__ __launch_bounds__(512) void gemm_qk(
    const uchar_t* __restrict__ A, long long sA, int lda,
    const uchar_t* __restrict__ B, long long sB, int ldb,
    int K, int ldc, uchar_t* __restrict__ outp, long long sC,
    float scale, float* __restrict__ rowpart) {
  constexpr int ABY = 16384;        // A region: 256 rows x 64B (16 chunks)
  constexpr int SBB = ABY + 8192;   // + B region: 128 rows x 64B = 24576
  constexpr int CPW = 3;            // 24 1KB chunks / 8 waves
  __shared__ __align__(16) uchar_t Ls[2][SBB];
  __shared__ float rsum[256];

  // bijective XCD swizzle (nx*ny = 512, divisible by 8)
  unsigned nx = gridDim.x, ny = gridDim.y;
  unsigned id = (blockIdx.z * ny + blockIdx.y) * nx + blockIdx.x;
  unsigned pb8 = (nx * ny) >> 3;
  unsigned cc = id & 7, j = id >> 3;
  int bz = j / pb8;
  unsigned jb = j - bz * pb8;
  unsigned jy = jb / nx;
  int by = cc * (ny >> 3) + jy;
  int bx = jb - jy * nx;

  int m0 = by * 256, n0 = bx * 128;
  int t = threadIdx.x;
  int lane = t & 63;
  int quad = lane >> 4, l16 = lane & 15;
  int wave = t >> 6;                       // 0..7
  int wm = (wave >> 1) * 32, wn = (wave & 1) * 64;  // per-half 32x128 tiles

  f32x4 acc[2][2][4];                      // [h][mi][ni], 64 VGPR
#pragma unroll
  for (int h = 0; h < 2; h++)
#pragma unroll
    for (int i = 0; i < 2; i++)
#pragma unroll
      for (int j4 = 0; j4 < 4; j4++)
#pragma unroll
        for (int r = 0; r < 4; r++) acc[h][i][j4][r] = 0.f;

  // seg-transposed staging: lane=(r16,quad) stages (row r16, 16B-seg quad) of
  // chunk c; LDS slot = c*1024 + r16*16 + quad*256.
  const uchar_t* gp[CPW];
  int lofs[CPW];
  int r16 = lane & 15, sseg = quad * 16;
#pragma unroll
  for (int i = 0; i < CPW; i++) {
    int c = wave * CPW + i;                // 0..23
    if (c < 16) {
      gp[i] = A + (size_t)bz * sA + (size_t)(m0 + c * 16 + r16) * lda + sseg;
      lofs[i] = c * 1024 + lane * 16;
    } else {
      int cb = c - 16;
      int slot = cb * 16 + r16;
      int arow = (slot & ~63) + ((slot & 15) * 4) + ((slot & 63) >> 4);
      gp[i] = B + (size_t)bz * sB + (size_t)(n0 + arow) * ldb + sseg;
      lofs[i] = ABY + cb * 1024 + lane * 16;
    }
  }
  char* lbase = (char*)&Ls[0][0];

  const int NT = K >> 6;  // 8 K-tiles of 64B
  // prologue: stage tiles 0 and 1 (6 loads in flight per wave)
#pragma unroll
  for (int i = 0; i < CPW; i++) gload16(gp[i], lbase + lofs[i]);
#pragma unroll
  for (int i = 0; i < CPW; i++) gload16(gp[i] + 64, lbase + SBB + lofs[i]);

  int vbase = l16 * 16 + (quad >> 1) * 256 + (quad & 1) * 8;
  for (int kt = 0; kt < NT; ++kt) {
    if (kt < NT - 1)
      asm volatile("s_waitcnt vmcnt(3)" ::: "memory");
    else
      asm volatile("s_waitcnt vmcnt(0)" ::: "memory");
    __builtin_amdgcn_s_barrier();
    const uchar_t* Lp = &Ls[kt & 1][0];
    __builtin_amdgcn_s_setprio(1);
#pragma unroll
    for (int s = 0; s < 2; s++) {
      long long af[2][2], bfv[4];
#pragma unroll
      for (int h = 0; h < 2; h++)
#pragma unroll
        for (int i = 0; i < 2; i++)
          af[h][i] = *(const long long*)&Lp[h * 8192 + wm * 64 + i * 1024 + s * 512 + vbase];
#pragma unroll
      for (int j4 = 0; j4 < 4; j4++)
        bfv[j4] = *(const long long*)&Lp[ABY + wn * 64 + j4 * 1024 + s * 512 + vbase];
#pragma unroll
      for (int h = 0; h < 2; h++)
#pragma unroll
        for (int mi = 0; mi < 2; mi++)
#pragma unroll
          for (int ni = 0; ni < 4; ni++)
            acc[h][mi][ni] = __builtin_amdgcn_mfma_f32_16x16x32_fp8_fp8(af[h][mi], bfv[ni], acc[h][mi][ni], 0, 0, 0);
    }
    __builtin_amdgcn_s_setprio(0);
    if (kt + 2 < NT) {
      asm volatile("s_waitcnt lgkmcnt(0)" ::: "memory");
      __builtin_amdgcn_sched_barrier(0);
      __builtin_amdgcn_s_barrier();
      int pofs = (kt & 1) * SBB;
      int ko = (kt + 2) * 64;
#pragma unroll
      for (int i = 0; i < CPW; i++)
        gload16(gp[i] + ko, lbase + pofs + lofs[i]);
    }
  }

  // zero the per-wg rowsum tally, then epilogue with LDS-only reduction
  if (t < 256) rsum[t] = 0.f;
  __syncthreads();

  size_t cbase = (size_t)bz * sC;
  int gnb = n0 + wn + l16 * 4;
#pragma unroll
  for (int h = 0; h < 2; h++) {
#pragma unroll
    for (int mi = 0; mi < 2; mi++) {
#pragma unroll
      for (int r = 0; r < 4; r++) {
        int mrow = h * 128 + wm + mi * 16 + quad * 4 + r;  // 0..255
        int m = m0 + mrow;
        float v4[4];
        float rs = 0.f;
#pragma unroll
        for (int ni = 0; ni < 4; ni++) {
          v4[ni] = __expf(acc[h][mi][ni][r] * scale) * 0.0625f;
          rs += v4[ni];
        }
        unsigned w = __builtin_amdgcn_cvt_pk_fp8_f32(v4[0], v4[1], 0u, false);
        w = __builtin_amdgcn_cvt_pk_fp8_f32(v4[2], v4[3], w, true);
        *(unsigned*)&outp[cbase + (size_t)m * ldc + gnb] = w;
        rs += __shfl_xor(rs, 1, 64);
        rs += __shfl_xor(rs, 2, 64);
        rs += __shfl_xor(rs, 4, 64);
        rs += __shfl_xor(rs, 8, 64);
        if (l16 == 0) atomicAdd(&rsum[mrow], rs);  // LDS, 2 contenders/row
      }
    }
  }
  __syncthreads();
  // collision-free partial store: part[bz][bx][m0 + t]
  if (t < 256) rowpart[((size_t)bz * 32 + bx) * 4096 + m0 + t] = rsum[t];
}

// ---------------- PV: OT = P' * V^T, bf16 out ---------------------------------
// BM=256 (MH=2), BN=64, BKB=128 swizzled row-major layout + depth-2
// counted-vmcnt pipeline (refcheck-proven rounds 8-14). acc 64 VGPR;
// 256 wg = 1 grid round.
__global__ __launch_bounds__(256) void gemm_pv(
    const uchar_t* __restrict__ A, long long sA, int lda,
    const uchar_t* __restrict__ B, long long sB, int ldb,
    int K, int ldc, ushort_t* __restrict__ outp, long long sC) {
  constexpr int BASEB = 32768;        // A region: 256 rows x 128B
  constexpr int SBB = BASEB + 8192;   // + B region: 64 rows x 128B = 40960
  constexpr int NL = SBB / 4096;      // 10 staging loads per thread per tile
  __shared__ __align__(16) uchar_t Ls[2][SBB];

  unsigned nx = gridDim.x, ny = gridDim.y;
  unsigned id = (blockIdx.z * ny + blockIdx.y) * nx + blockIdx.x;
  unsigned pb8 = (nx * ny) >> 3;
  unsigned cc = id & 7, j = id >> 3;
  int bz = j / pb8;
  unsigned jb = j - bz * pb8;
  unsigned jy = jb / nx;
  int by = cc * (ny >> 3) + jy;
  int bx = jb - jy * nx;

  int m0 = by * 256, n0 = bx * 64;
  int t = threadIdx.x;
  int lane = t & 63;
  int quad = lane >> 4, l16 = lane & 15;
  int wave = t >> 6;
  int wm = wave * 32;  // per-half 32x64 wave tile

  f32x4 acc[2][2][4];
#pragma unroll
  for (int h = 0; h < 2; h++)
#pragma unroll
    for (int i = 0; i < 2; i++)
#pragma unroll
      for (int j4 = 0; j4 < 4; j4++)
#pragma unroll
        for (int r = 0; r < 4; r++) acc[h][i][j4][r] = 0.f;

  // row-major 128B rows with XOR swizzle on kb (both sides, rule #21)
  const uchar_t* gp[NL];
  int lofs[NL];
#pragma unroll
  for (int i = 0; i < NL; i++) {
    int o = i * 4096 + t * 16;
    int row = o >> 7;
    int kb = (o & 127) ^ ((row & 7) << 4);
    if (row < 256) {
      gp[i] = A + (size_t)bz * sA + (size_t)(m0 + row) * lda + kb;
    } else {
      int br = row - 256;  // 0..63, single 64-row group
      int ar = (br & 15) * 4 + (br >> 4);
      gp[i] = B + (size_t)bz * sB + (size_t)(n0 + ar) * ldb + kb;
    }
    lofs[i] = o;
  }
  char* lbase = (char*)&Ls[0][0];

  const int NT = K >> 7;  // 32
  // prologue: stage tiles 0 and 1
#pragma unroll
  for (int i = 0; i < NL; i++) gload16(gp[i], lbase + lofs[i]);
#pragma unroll
  for (int i = 0; i < NL; i++) gload16(gp[i] + 128, lbase + SBB + lofs[i]);

  int swz = (l16 & 7) << 4;
  for (int kt = 0; kt < NT; ++kt) {
    if (kt < NT - 1)
      asm volatile("s_waitcnt vmcnt(10)" ::: "memory");
    else
      asm volatile("s_waitcnt vmcnt(0)" ::: "memory");
    __builtin_amdgcn_s_barrier();
    const uchar_t* Lp = &Ls[kt & 1][0];
    __builtin_amdgcn_s_setprio(1);
#pragma unroll
    for (int ks = 0; ks < 4; ks++) {
      int kx = (ks * 32 + quad * 8) ^ swz;
      long long af[2][2], bfv[4];
#pragma unroll
      for (int h = 0; h < 2; h++)
#pragma unroll
        for (int i = 0; i < 2; i++)
          af[h][i] = *(const long long*)&Lp[(h * 128 + wm + i * 16 + l16) * 128 + kx];
#pragma unroll
      for (int j4 = 0; j4 < 4; j4++)
        bfv[j4] = *(const long long*)&Lp[BASEB + (j4 * 16 + l16) * 128 + kx];
#pragma unroll
      for (int h = 0; h < 2; h++)
#pragma unroll
        for (int mi = 0; mi < 2; mi++)
#pragma unroll
          for (int ni = 0; ni < 4; ni++)
            acc[h][mi][ni] = __builtin_amdgcn_mfma_f32_16x16x32_fp8_fp8(af[h][mi], bfv[ni], acc[h][mi][ni], 0, 0, 0);
    }
    __builtin_amdgcn_s_setprio(0);
    if (kt + 2 < NT) {
      asm volatile("s_waitcnt lgkmcnt(0)" ::: "memory");
      __builtin_amdgcn_sched_barrier(0);
      __builtin_amdgcn_s_barrier();
      int pofs = (kt & 1) * SBB;
      int ko = (kt + 2) * 128;
#pragma unroll
      for (int i = 0; i < NL; i++)
        gload16(gp[i] + ko, lbase + pofs + lofs[i]);
    }
  }

  size_t cbase = (size_t)bz * sC;
  int gnb = n0 + l16 * 4;
#pragma unroll
  for (int h = 0; h < 2; h++) {
#pragma unroll
    for (int mi = 0; mi < 2; mi++) {
#pragma unroll
      for (int r = 0; r < 4; r++) {
        int m = m0 + h * 128 + wm + mi * 16 + quad * 4 + r;
        unsigned lo = (unsigned)f2bf(acc[h][mi][0][r]) | ((unsigned)f2bf(acc[h][mi][1][r]) << 16);
        unsigned hi = (unsigned)f2bf(acc[h][mi][2][r]) | ((unsigned)f2bf(acc[h][mi][3][r]) << 16);
        *(uint2*)&outp[cbase + (size_t)m * ldc + gnb] = make_uint2(lo, hi);
      }
    }
  }
}

extern "C" void kernel_launch(void* const* d_in, const int* in_sizes, int n_in,
                              void* d_out, int out_size, void* d_ws, size_t ws_size,
                              hipStream_t stream) {
  const float* x     = (const float*)d_in[0];
  const float* gamma = (const float*)d_in[1];
  const float* beta  = (const float*)d_in[2];
  const float* wq    = (const float*)d_in[3];
  const float* bq    = (const float*)d_in[4];
  const float* wk    = (const float*)d_in[5];
  const float* bk    = (const float*)d_in[6];
  const float* wv    = (const float*)d_in[7];
  const float* bv    = (const float*)d_in[8];
  const float* wo    = (const float*)d_in[9];
  const float* bo    = (const float*)d_in[10];
  float* out = (float*)d_out;

  // workspace layout
  ushort_t* wb  = (ushort_t*)d_ws;     // [wq;wk] 1024x512, wv, wo (bf16)
  ushort_t* wvb = wb + 524288;
  ushort_t* wob = wb + 786432;
  ushort_t* hnT = wb + 1048576;        // 2 x 4096 x 512 bf16
  uchar_t*  qk8 = (uchar_t*)(hnT + 4194304);  // 2 x 4096 x 1024 fp8 (q | k)
  uchar_t*  vC8 = qk8 + 8388608;       // 2 x 512 x 4096 fp8
  ushort_t* OT  = (ushort_t*)(vC8 + 4194304); // 2 x 4096 x 512 bf16
  uchar_t*  S8  = (uchar_t*)(OT + 4194304);   // 2 x 4096 x 4096 fp8 (P' = exp/16)
  float* fbuf   = (float*)(S8 + 33554432);
  float* stats  = fbuf;                // 128
  float* stats2 = fbuf + 128;          // 128
  float* qkbias = fbuf + 256;          // 1024
  float* l      = (float*)hnT;         // 2 x 4096 row sums (hnT dead after v-GEMM)
  float* lpart  = l + 8192;            // 2 x 32 x 4096 rowsum partials (1 MB)

  const long long HS = 2097152;   // 4096*512 per batch
  const long long QS = 4194304;   // 4096*1024 per batch (bytes, fp8)
  const long long SS = 16777216;  // 4096*4096 per batch (bytes, fp8)
  const float scale = 0.044194173824159216f;  // 512^-0.5

  cvt_weights<<<dim3(1029), dim3(256), 0, stream>>>(wq, wk, wv, wo, bq, bk, wb, qkbias, stats2);
  gn_stats_partial<<<dim3(256), dim3(256), 0, stream>>>(x, stats2);
  gn_finalize<<<dim3(1), dim3(64), 0, stream>>>(stats2, stats);
  gn_apply<<<dim3(128, 16, 2), dim3(32, 8), 0, stream>>>(x, gamma, beta, stats, hnT);
  // qk8 = hnT * [wq;wk]^T (M=4096, N=1024, K=512), packed col bias, fp8 out
  gemm_abt<128, 2><<<dim3(8, 32, 2), dim3(256), 0, stream>>>(
      hnT, HS, 512, wb, 0, 512, 512, 1024, 1024, (ushort_t*)qk8, QS, qkbias, 2, 1.f,
      nullptr, nullptr, nullptr, 1, 2);
  // vC8 = wv * hnT^T (M=512, N=4096, K=512), row bias, fp8 out; UNR=2
  gemm_abt<64, 2><<<dim3(64, 4, 2), dim3(256), 0, stream>>>(
      wvb, 0, 512, hnT, HS, 512, 512, 4096, 4096, (ushort_t*)vC8, HS, bv, 1, 1.f,
      nullptr, nullptr, nullptr, 0, 2);
  // P' = exp(scale * q*k^T)/16 fp8 + PRIVATE rowsum partials (no atomics)
  // BM=256 MH=2, 8 waves, depth-2 counted-vmcnt pipeline
  gemm_qk<<<dim3(32, 16, 2), dim3(512), 0, stream>>>(
      qk8, QS, 1024, qk8 + 512, QS, 1024, 512, 4096, S8, SS, scale, lpart);
  // l[bz][m] = sum_bx lpart[bz][bx][m]
  rowsum_reduce<<<dim3(32), dim3(256), 0, stream>>>(lpart, l);
  // OT = P' * vC8^T (M=4096, N=512, K=4096), bf16 out
  gemm_pv<<<dim3(8, 16, 2), dim3(256), 0, stream>>>(
      S8, SS, 4096, vC8, HS, 4096, 4096, 512, OT, HS);
  // y = wo * (OT/l')^T + bo + x (M=512, N=4096, K=512), fp32 + residual; UNR=2
  gemm_abt<64, 2><<<dim3(64, 4, 2), dim3(256), 0, stream>>>(
      wob, 0, 512, OT, HS, 512, 512, 4096, 4096, nullptr, HS, bo, 1, 1.f,
      out, x, l, 0, 1);
}

// Round 17
// 215.310 us; speedup vs baseline: 1.0192x; 1.0192x over previous
//
#include <hip/hip_runtime.h>

typedef unsigned short ushort_t;
typedef unsigned char uchar_t;
typedef __bf16 bf16x8 __attribute__((ext_vector_type(8)));
typedef float f32x4 __attribute__((ext_vector_type(4)));

__device__ __forceinline__ ushort_t f2bf(float f) {
  unsigned u = __float_as_uint(f);
  u += 0x7fff + ((u >> 16) & 1);
  return (ushort_t)(u >> 16);
}

__device__ __forceinline__ void gload16(const void* g, void* l) {
  __builtin_amdgcn_global_load_lds(
      (const __attribute__((address_space(1))) unsigned int*)g,
      (__attribute__((address_space(3))) unsigned int*)l, 16, 0, 0);
}

// ---------------- weight fp32 -> bf16, pack qk bias, zero stats2 ----------------
__global__ __launch_bounds__(256) void cvt_weights(
    const float* __restrict__ wq, const float* __restrict__ wk,
    const float* __restrict__ wv, const float* __restrict__ wo,
    const float* __restrict__ bq, const float* __restrict__ bk,
    ushort_t* __restrict__ dst, float* __restrict__ qkbias,
    float* __restrict__ stats2) {
  int b = blockIdx.x, t = threadIdx.x;
  if (b < 1024) {
    int i = b * 256 + t;
    dst[i]          = f2bf(wq[i]);
    dst[262144 + i] = f2bf(wk[i]);
    dst[524288 + i] = f2bf(wv[i]);
    dst[786432 + i] = f2bf(wo[i]);
  } else if (b < 1028) {
    int j = (b - 1024) * 256 + t;  // 0..1023
    qkbias[j] = (j < 512) ? bq[j] : bk[j - 512];
  } else {
    if (t < 128) stats2[t] = 0.f;
  }
}

// ---------------- rowsum partial reduce: l[bz][m] = sum_bx part[bz][bx][m] ----
__global__ __launch_bounds__(256) void rowsum_reduce(
    const float* __restrict__ part, float* __restrict__ l) {
  int i = blockIdx.x * 256 + threadIdx.x;   // 0..8191
  int bz = i >> 12, m = i & 4095;
  const float* p = part + (size_t)bz * 32 * 4096 + m;
  float s = 0.f;
#pragma unroll
  for (int bx = 0; bx < 32; bx++) s += p[(size_t)bx * 4096];
  l[i] = s;
}

// ---------------- group norm partial stats: 4 blocks per (b,g) ----------------
__global__ __launch_bounds__(256) void gn_stats_partial(const float* __restrict__ x,
                                                        float* __restrict__ stats2) {
  int bg = blockIdx.x >> 2, q = blockIdx.x & 3;
  const float4* p = (const float4*)(x + (size_t)bg * 65536 + q * 16384);
  float s = 0.f, ss = 0.f;
  for (int i = threadIdx.x; i < 4096; i += 256) {
    float4 v = p[i];
    s += v.x + v.y + v.z + v.w;
    ss += v.x * v.x + v.y * v.y + v.z * v.z + v.w * v.w;
  }
  for (int off = 32; off; off >>= 1) {
    s += __shfl_xor(s, off, 64);
    ss += __shfl_xor(ss, off, 64);
  }
  __shared__ float sh[8];
  int wave = threadIdx.x >> 6, lane = threadIdx.x & 63;
  if (lane == 0) { sh[wave] = s; sh[4 + wave] = ss; }
  __syncthreads();
  if (threadIdx.x == 0) {
    atomicAdd(&stats2[bg * 2], sh[0] + sh[1] + sh[2] + sh[3]);
    atomicAdd(&stats2[bg * 2 + 1], sh[4] + sh[5] + sh[6] + sh[7]);
  }
}

__global__ __launch_bounds__(64) void gn_finalize(const float* __restrict__ stats2,
                                                  float* __restrict__ stats) {
  int t = threadIdx.x;  // 64 groups total (2 batches x 32)
  float s = stats2[t * 2], ss = stats2[t * 2 + 1];
  float mean = s * (1.f / 65536.f);
  float var = ss * (1.f / 65536.f) - mean * mean;
  stats[t * 2] = mean;
  stats[t * 2 + 1] = rsqrtf(var + 1e-6f);
}

// ---------------- GN apply + transpose: x (b,c,n) -> hnT (b,n,c) bf16 ----------------
__global__ __launch_bounds__(256) void gn_apply(
    const float* __restrict__ x, const float* __restrict__ gamma,
    const float* __restrict__ beta, const float* __restrict__ stats,
    ushort_t* __restrict__ hnT) {
  __shared__ float T[32][33];
  int i0 = blockIdx.x * 32, c0 = blockIdx.y * 32, b = blockIdx.z;
  int tx = threadIdx.x, ty = threadIdx.y;  // (32,8)
#pragma unroll
  for (int k = 0; k < 4; k++) {
    int cl = ty + k * 8;
    int c = c0 + cl;
    int bg = (b * 32 + (c >> 4)) * 2;
    float mean = stats[bg], rstd = stats[bg + 1];
    float v = x[((size_t)(b * 512 + c)) * 4096 + i0 + tx];
    T[cl][tx] = (v - mean) * rstd * gamma[c] + beta[c];
  }
  __syncthreads();
#pragma unroll
  for (int k = 0; k < 4; k++) {
    int il = ty + k * 8;
    hnT[((size_t)b * 4096 + i0 + il) * 512 + c0 + tx] = f2bf(T[tx][il]);
  }
}

// ---------------- bf16 C = A * B^T GEMM, 128 x BN tile, UNR k-chunks/buffer --
// UNR=2 for the 512-wg (2 wg/CU, grid-limited) launches: halves the
// barrier+drain count (round-4: −8us across the three abt launches).
// omode: 0 = bf16 out, 1 = fp32 + residual, 2 = fp8 e4m3 out.
template <int BN, int UNR>
__global__ __launch_bounds__(256) void gemm_abt(
    const ushort_t* __restrict__ A, long long sA, int lda,
    const ushort_t* __restrict__ B, long long sB, int ldb,
    int K, int N, int ldc,
    ushort_t* __restrict__ outB, long long sC,
    const float* __restrict__ bias, int bias_mode, float scale,
    float* __restrict__ outF, const float* __restrict__ resid,
    const float* __restrict__ colscale, int swiz, int omode) {
  constexpr int CPW = (8 + BN / 16) / 4;
  constexpr int SB = (128 + BN) * 32;      // halfwords per 32-elem k-chunk
  constexpr int STEP = 32 * UNR;
  constexpr int MI = (BN == 128) ? 4 : 2;
  constexpr int NI = 4;
  __shared__ __align__(16) ushort_t Ls[2][UNR * SB];

  int bx = blockIdx.x, by = blockIdx.y, bz = blockIdx.z;
  if (swiz) {
    unsigned nx = gridDim.x, ny = gridDim.y;
    unsigned id = (blockIdx.z * ny + blockIdx.y) * nx + blockIdx.x;
    unsigned pb8 = (nx * ny) >> 3;
    unsigned c = id & 7, j = id >> 3;
    bz = j / pb8;
    unsigned jb = j - bz * pb8;
    unsigned jy = jb / nx;
    by = c * (ny >> 3) + jy;
    bx = jb - jy * nx;
  }

  int m0 = by * 128, n0 = bx * BN;
  int t = threadIdx.x;
  int lane = t & 63;
  int quad = lane >> 4, l16 = lane & 15;
  int wave = t >> 6;
  int wm = (BN == 128) ? (wave >> 1) * 64 : wave * 32;
  int wn = (BN == 128) ? (wave & 1) * 64 : 0;

  f32x4 acc[MI][NI];
#pragma unroll
  for (int i = 0; i < MI; i++)
#pragma unroll
    for (int j = 0; j < NI; j++)
#pragma unroll
      for (int r = 0; r < 4; r++) acc[i][j][r] = 0.f;

  const ushort_t* gp[CPW];
  int lofs[CPW];
  int crow = lane >> 2, skoff = (lane & 3) * 8;
#pragma unroll
  for (int i = 0; i < CPW; i++) {
    int c = wave * CPW + i;
    if (c < 8) {
      gp[i] = A + (size_t)bz * sA + (size_t)(m0 + c * 16 + crow) * lda + skoff;
      lofs[i] = c * 1024 + lane * 16;
    } else {
      int slot = (c - 8) * 16 + crow;
      int arow = (slot & ~63) + ((slot & 15) * 4) + ((slot & 63) >> 4);
      gp[i] = B + (size_t)bz * sB + (size_t)(n0 + arow) * ldb + skoff;
      lofs[i] = 8192 + (c - 8) * 1024 + lane * 16;
    }
  }
  char* lbase = (char*)&Ls[0][0];

#pragma unroll
  for (int s = 0; s < UNR; s++)
#pragma unroll
    for (int i = 0; i < CPW; i++)
      gload16(gp[i] + s * 32, lbase + s * (SB * 2) + lofs[i]);

  for (int k0 = 0; k0 < K; k0 += STEP) {
    int p = (k0 / STEP) & 1;
    __syncthreads();
    if (k0 + STEP < K) {
      int pofs = (p ^ 1) * (UNR * SB * 2);
#pragma unroll
      for (int s = 0; s < UNR; s++)
#pragma unroll
        for (int i = 0; i < CPW; i++)
          gload16(gp[i] + k0 + STEP + s * 32, lbase + pofs + s * (SB * 2) + lofs[i]);
    }
#pragma unroll
    for (int s = 0; s < UNR; s++) {
      bf16x8 af[MI], bfr[NI];
#pragma unroll
      for (int i = 0; i < MI; i++)
        af[i] = *(const bf16x8*)&Ls[p][s * SB + (wm + i * 16 + l16) * 32 + quad * 8];
#pragma unroll
      for (int j = 0; j < NI; j++)
        bfr[j] = *(const bf16x8*)&Ls[p][s * SB + 4096 + (wn + j * 16 + l16) * 32 + quad * 8];
#pragma unroll
      for (int mi = 0; mi < MI; mi++)
#pragma unroll
        for (int ni = 0; ni < NI; ni++)
          acc[mi][ni] = __builtin_amdgcn_mfma_f32_16x16x32_bf16(af[mi], bfr[ni], acc[mi][ni], 0, 0, 0);
    }
  }

  size_t cbase = (size_t)bz * sC;
  int gnb = n0 + wn + l16 * 4;
  float cs4[4] = {1.f, 1.f, 1.f, 1.f};
  if (colscale) {
    float4 c4 = *(const float4*)&colscale[(size_t)bz * N + gnb];
    cs4[0] = 1.f / c4.x; cs4[1] = 1.f / c4.y; cs4[2] = 1.f / c4.z; cs4[3] = 1.f / c4.w;
  }
  float b4[4] = {0.f, 0.f, 0.f, 0.f};
  if (bias_mode == 2) {
    float4 t4 = *(const float4*)&bias[gnb];
    b4[0] = t4.x; b4[1] = t4.y; b4[2] = t4.z; b4[3] = t4.w;
  }
#pragma unroll
  for (int mi = 0; mi < MI; mi++) {
#pragma unroll
    for (int r = 0; r < 4; r++) {
      int m = m0 + wm + mi * 16 + quad * 4 + r;
      float rbias = (bias_mode == 1) ? bias[m] : 0.f;
      float v4[4];
#pragma unroll
      for (int ni = 0; ni < NI; ni++) {
        float val = acc[mi][ni][r];
        if (colscale) val *= cs4[ni];
        val += (bias_mode == 2) ? b4[ni] : rbias;
        val *= scale;
        v4[ni] = val;
      }
      size_t idx = cbase + (size_t)m * ldc + gnb;
      if (omode == 1) {
        float4 rv = *(const float4*)&resid[idx];
        float4 ov = make_float4(v4[0] + rv.x, v4[1] + rv.y, v4[2] + rv.z, v4[3] + rv.w);
        *(float4*)&outF[idx] = ov;
      } else if (omode == 2) {
        unsigned w = __builtin_amdgcn_cvt_pk_fp8_f32(v4[0], v4[1], 0u, false);
        w = __builtin_amdgcn_cvt_pk_fp8_f32(v4[2], v4[3], w, true);
        *(unsigned*)&((uchar_t*)outB)[idx] = w;
      } else {
        unsigned lo = (unsigned)f2bf(v4[0]) | ((unsigned)f2bf(v4[1]) << 16);
        unsigned hi = (unsigned)f2bf(v4[2]) | ((unsigned)f2bf(v4[3]) << 16);
        *(uint2*)&outB[idx] = make_uint2(lo, hi);
      }
    }
  }
}

// ---------------- QK: S' = exp(scale*Q.K^T)/16 fp8 + PRIVATE rowsum ----------
// BM=256 x BN=128 tile, 8 waves (512 thr), BKB=64 seg-transposed, 2-phase.
// Round-14 proven config (46.3us, MfmaUtil 29): fixed-cost amortization via
// MH=2 with acc[2][2][4]=64 VGPR (round-8 VGPR lesson respected). 1024 wg,
// 48KB LDS -> 3 wg/CU. Round-15's counted-vmcnt graft was a tie (45.0 within
// noise); round-16's qkproj attempt introduced a replay race — both reverted
// to this known-good state (race surface minimized: plain __syncthreads).
// Epilogue: LDS-only rowsum (rsum[256], 2 contenders/row) -> collision-free
// partial store; rowsum_reduce sums the 32 bx-partials.
__global__ __launch_bounds__(512) void gemm_qk(
    const uchar_t* __restrict__ A, long long sA, int lda,
    const uchar_t* __restrict__ B, long long sB, int ldb,
    int K, int ldc, uchar_t* __restrict__ outp, long long sC,
    float scale, float* __restrict__ rowpart) {
  constexpr int ABY = 16384;        // A region: 256 rows x 64B (16 chunks)
  constexpr int SBB = ABY + 8192;   // + B region: 128 rows x 64B = 24576
  constexpr int CPW = 3;            // 24 1KB chunks / 8 waves
  __shared__ __align__(16) uchar_t Ls[2][SBB];
  __shared__ float rsum[256];

  // bijective XCD swizzle (nx*ny = 512, divisible by 8)
  unsigned nx = gridDim.x, ny = gridDim.y;
  unsigned id = (blockIdx.z * ny + blockIdx.y) * nx + blockIdx.x;
  unsigned pb8 = (nx * ny) >> 3;
  unsigned cc = id & 7, j = id >> 3;
  int bz = j / pb8;
  unsigned jb = j - bz * pb8;
  unsigned jy = jb / nx;
  int by = cc * (ny >> 3) + jy;
  int bx = jb - jy * nx;

  int m0 = by * 256, n0 = bx * 128;
  int t = threadIdx.x;
  int lane = t & 63;
  int quad = lane >> 4, l16 = lane & 15;
  int wave = t >> 6;                       // 0..7
  int wm = (wave >> 1) * 32, wn = (wave & 1) * 64;  // per-half 32x128 tiles

  f32x4 acc[2][2][4];                      // [h][mi][ni], 64 VGPR
#pragma unroll
  for (int h = 0; h < 2; h++)
#pragma unroll
    for (int i = 0; i < 2; i++)
#pragma unroll
      for (int j4 = 0; j4 < 4; j4++)
#pragma unroll
        for (int r = 0; r < 4; r++) acc[h][i][j4][r] = 0.f;

  // seg-transposed staging: lane=(r16,quad) stages (row r16, 16B-seg quad) of
  // chunk c; LDS slot = c*1024 + r16*16 + quad*256. Fragment b64 reads are
  // conflict-free per half-wave (m136; round-0-proven layout family).
  const uchar_t* gp[CPW];
  int lofs[CPW];
  int r16 = lane & 15, sseg = quad * 16;
#pragma unroll
  for (int i = 0; i < CPW; i++) {
    int c = wave * CPW + i;                // 0..23
    if (c < 16) {
      gp[i] = A + (size_t)bz * sA + (size_t)(m0 + c * 16 + r16) * lda + sseg;
      lofs[i] = c * 1024 + lane * 16;
    } else {
      int cb = c - 16;
      int slot = cb * 16 + r16;
      int arow = (slot & ~63) + ((slot & 15) * 4) + ((slot & 63) >> 4);
      gp[i] = B + (size_t)bz * sB + (size_t)(n0 + arow) * ldb + sseg;
      lofs[i] = ABY + cb * 1024 + lane * 16;
    }
  }
  char* lbase = (char*)&Ls[0][0];

#pragma unroll
  for (int i = 0; i < CPW; i++) gload16(gp[i], lbase + lofs[i]);

  int vbase = l16 * 16 + (quad >> 1) * 256 + (quad & 1) * 8;
  for (int k0 = 0; k0 < K; k0 += 64) {
    int p = (k0 >> 6) & 1;
    __syncthreads();
    if (k0 + 64 < K) {
      int pofs = (p ^ 1) * SBB;
#pragma unroll
      for (int i = 0; i < CPW; i++)
        gload16(gp[i] + k0 + 64, lbase + pofs + lofs[i]);
    }
    const uchar_t* Lp = &Ls[p][0];
#pragma unroll
    for (int s = 0; s < 2; s++) {
      long long af[2][2], bfv[4];
#pragma unroll
      for (int h = 0; h < 2; h++)
#pragma unroll
        for (int i = 0; i < 2; i++)
          af[h][i] = *(const long long*)&Lp[h * 8192 + wm * 64 + i * 1024 + s * 512 + vbase];
#pragma unroll
      for (int j4 = 0; j4 < 4; j4++)
        bfv[j4] = *(const long long*)&Lp[ABY + wn * 64 + j4 * 1024 + s * 512 + vbase];
#pragma unroll
      for (int h = 0; h < 2; h++)
#pragma unroll
        for (int mi = 0; mi < 2; mi++)
#pragma unroll
          for (int ni = 0; ni < 4; ni++)
            acc[h][mi][ni] = __builtin_amdgcn_mfma_f32_16x16x32_fp8_fp8(af[h][mi], bfv[ni], acc[h][mi][ni], 0, 0, 0);
    }
  }

  // zero the per-wg rowsum tally, then epilogue with LDS-only reduction
  if (t < 256) rsum[t] = 0.f;
  __syncthreads();

  size_t cbase = (size_t)bz * sC;
  int gnb = n0 + wn + l16 * 4;
#pragma unroll
  for (int h = 0; h < 2; h++) {
#pragma unroll
    for (int mi = 0; mi < 2; mi++) {
#pragma unroll
      for (int r = 0; r < 4; r++) {
        int mrow = h * 128 + wm + mi * 16 + quad * 4 + r;  // 0..255
        int m = m0 + mrow;
        float v4[4];
        float rs = 0.f;
#pragma unroll
        for (int ni = 0; ni < 4; ni++) {
          v4[ni] = __expf(acc[h][mi][ni][r] * scale) * 0.0625f;
          rs += v4[ni];
        }
        unsigned w = __builtin_amdgcn_cvt_pk_fp8_f32(v4[0], v4[1], 0u, false);
        w = __builtin_amdgcn_cvt_pk_fp8_f32(v4[2], v4[3], w, true);
        *(unsigned*)&outp[cbase + (size_t)m * ldc + gnb] = w;
        rs += __shfl_xor(rs, 1, 64);
        rs += __shfl_xor(rs, 2, 64);
        rs += __shfl_xor(rs, 4, 64);
        rs += __shfl_xor(rs, 8, 64);
        if (l16 == 0) atomicAdd(&rsum[mrow], rs);  // LDS, 2 contenders/row
      }
    }
  }
  __syncthreads();
  // collision-free partial store: part[bz][bx][m0 + t]
  if (t < 256) rowpart[((size_t)bz * 32 + bx) * 4096 + m0 + t] = rsum[t];
}

// ---------------- PV: OT = P' * V^T, bf16 out ---------------------------------
// BM=256 (MH=2), BN=64, BKB=128 swizzled row-major layout + depth-2
// counted-vmcnt pipeline (refcheck-proven rounds 8-15). acc 64 VGPR;
// 256 wg = 1 grid round.
__global__ __launch_bounds__(256) void gemm_pv(
    const uchar_t* __restrict__ A, long long sA, int lda,
    const uchar_t* __restrict__ B, long long sB, int ldb,
    int K, int ldc, ushort_t* __restrict__ outp, long long sC) {
  constexpr int BASEB = 32768;        // A region: 256 rows x 128B
  constexpr int SBB = BASEB + 8192;   // + B region: 64 rows x 128B = 40960
  constexpr int NL = SBB / 4096;      // 10 staging loads per thread per tile
  __shared__ __align__(16) uchar_t Ls[2][SBB];

  unsigned nx = gridDim.x, ny = gridDim.y;
  unsigned id = (blockIdx.z * ny + blockIdx.y) * nx + blockIdx.x;
  unsigned pb8 = (nx * ny) >> 3;
  unsigned cc = id & 7, j = id >> 3;
  int bz = j / pb8;
  unsigned jb = j - bz * pb8;
  unsigned jy = jb / nx;
  int by = cc * (ny >> 3) + jy;
  int bx = jb - jy * nx;

  int m0 = by * 256, n0 = bx * 64;
  int t = threadIdx.x;
  int lane = t & 63;
  int quad = lane >> 4, l16 = lane & 15;
  int wave = t >> 6;
  int wm = wave * 32;  // per-half 32x64 wave tile

  f32x4 acc[2][2][4];
#pragma unroll
  for (int h = 0; h < 2; h++)
#pragma unroll
    for (int i = 0; i < 2; i++)
#pragma unroll
      for (int j4 = 0; j4 < 4; j4++)
#pragma unroll
        for (int r = 0; r < 4; r++) acc[h][i][j4][r] = 0.f;

  // row-major 128B rows with XOR swizzle on kb (both sides, rule #21)
  const uchar_t* gp[NL];
  int lofs[NL];
#pragma unroll
  for (int i = 0; i < NL; i++) {
    int o = i * 4096 + t * 16;
    int row = o >> 7;
    int kb = (o & 127) ^ ((row & 7) << 4);
    if (row < 256) {
      gp[i] = A + (size_t)bz * sA + (size_t)(m0 + row) * lda + kb;
    } else {
      int br = row - 256;  // 0..63, single 64-row group
      int ar = (br & 15) * 4 + (br >> 4);
      gp[i] = B + (size_t)bz * sB + (size_t)(n0 + ar) * ldb + kb;
    }
    lofs[i] = o;
  }
  char* lbase = (char*)&Ls[0][0];

  const int NT = K >> 7;  // 32
  // prologue: stage tiles 0 and 1
#pragma unroll
  for (int i = 0; i < NL; i++) gload16(gp[i], lbase + lofs[i]);
#pragma unroll
  for (int i = 0; i < NL; i++) gload16(gp[i] + 128, lbase + SBB + lofs[i]);

  int swz = (l16 & 7) << 4;
  for (int kt = 0; kt < NT; ++kt) {
    if (kt < NT - 1)
      asm volatile("s_waitcnt vmcnt(10)" ::: "memory");
    else
      asm volatile("s_waitcnt vmcnt(0)" ::: "memory");
    __builtin_amdgcn_s_barrier();
    const uchar_t* Lp = &Ls[kt & 1][0];
    __builtin_amdgcn_s_setprio(1);
#pragma unroll
    for (int ks = 0; ks < 4; ks++) {
      int kx = (ks * 32 + quad * 8) ^ swz;
      long long af[2][2], bfv[4];
#pragma unroll
      for (int h = 0; h < 2; h++)
#pragma unroll
        for (int i = 0; i < 2; i++)
          af[h][i] = *(const long long*)&Lp[(h * 128 + wm + i * 16 + l16) * 128 + kx];
#pragma unroll
      for (int j4 = 0; j4 < 4; j4++)
        bfv[j4] = *(const long long*)&Lp[BASEB + (j4 * 16 + l16) * 128 + kx];
#pragma unroll
      for (int h = 0; h < 2; h++)
#pragma unroll
        for (int mi = 0; mi < 2; mi++)
#pragma unroll
          for (int ni = 0; ni < 4; ni++)
            acc[h][mi][ni] = __builtin_amdgcn_mfma_f32_16x16x32_fp8_fp8(af[h][mi], bfv[ni], acc[h][mi][ni], 0, 0, 0);
    }
    __builtin_amdgcn_s_setprio(0);
    if (kt + 2 < NT) {
      asm volatile("s_waitcnt lgkmcnt(0)" ::: "memory");
      __builtin_amdgcn_sched_barrier(0);
      __builtin_amdgcn_s_barrier();
      int pofs = (kt & 1) * SBB;
      int ko = (kt + 2) * 128;
#pragma unroll
      for (int i = 0; i < NL; i++)
        gload16(gp[i] + ko, lbase + pofs + lofs[i]);
    }
  }

  size_t cbase = (size_t)bz * sC;
  int gnb = n0 + l16 * 4;
#pragma unroll
  for (int h = 0; h < 2; h++) {
#pragma unroll
    for (int mi = 0; mi < 2; mi++) {
#pragma unroll
      for (int r = 0; r < 4; r++) {
        int m = m0 + h * 128 + wm + mi * 16 + quad * 4 + r;
        unsigned lo = (unsigned)f2bf(acc[h][mi][0][r]) | ((unsigned)f2bf(acc[h][mi][1][r]) << 16);
        unsigned hi = (unsigned)f2bf(acc[h][mi][2][r]) | ((unsigned)f2bf(acc[h][mi][3][r]) << 16);
        *(uint2*)&outp[cbase + (size_t)m * ldc + gnb] = make_uint2(lo, hi);
      }
    }
  }
}

extern "C" void kernel_launch(void* const* d_in, const int* in_sizes, int n_in,
                              void* d_out, int out_size, void* d_ws, size_t ws_size,
                              hipStream_t stream) {
  const float* x     = (const float*)d_in[0];
  const float* gamma = (const float*)d_in[1];
  const float* beta  = (const float*)d_in[2];
  const float* wq    = (const float*)d_in[3];
  const float* bq    = (const float*)d_in[4];
  const float* wk    = (const float*)d_in[5];
  const float* bk    = (const float*)d_in[6];
  const float* wv    = (const float*)d_in[7];
  const float* bv    = (const float*)d_in[8];
  const float* wo    = (const float*)d_in[9];
  const float* bo    = (const float*)d_in[10];
  float* out = (float*)d_out;

  // workspace layout
  ushort_t* wb  = (ushort_t*)d_ws;     // [wq;wk] 1024x512, wv, wo (bf16)
  ushort_t* wvb = wb + 524288;
  ushort_t* wob = wb + 786432;
  ushort_t* hnT = wb + 1048576;        // 2 x 4096 x 512 bf16
  uchar_t*  qk8 = (uchar_t*)(hnT + 4194304);  // 2 x 4096 x 1024 fp8 (q | k)
  uchar_t*  vC8 = qk8 + 8388608;       // 2 x 512 x 4096 fp8
  ushort_t* OT  = (ushort_t*)(vC8 + 4194304); // 2 x 4096 x 512 bf16
  uchar_t*  S8  = (uchar_t*)(OT + 4194304);   // 2 x 4096 x 4096 fp8 (P' = exp/16)
  float* fbuf   = (float*)(S8 + 33554432);
  float* stats  = fbuf;                // 128
  float* stats2 = fbuf + 128;          // 128
  float* qkbias = fbuf + 256;          // 1024
  float* l      = (float*)hnT;         // 2 x 4096 row sums (hnT dead after v-GEMM)
  float* lpart  = l + 8192;            // 2 x 32 x 4096 rowsum partials (1 MB)

  const long long HS = 2097152;   // 4096*512 per batch
  const long long QS = 4194304;   // 4096*1024 per batch (bytes, fp8)
  const long long SS = 16777216;  // 4096*4096 per batch (bytes, fp8)
  const float scale = 0.044194173824159216f;  // 512^-0.5

  cvt_weights<<<dim3(1029), dim3(256), 0, stream>>>(wq, wk, wv, wo, bq, bk, wb, qkbias, stats2);
  gn_stats_partial<<<dim3(256), dim3(256), 0, stream>>>(x, stats2);
  gn_finalize<<<dim3(1), dim3(64), 0, stream>>>(stats2, stats);
  gn_apply<<<dim3(128, 16, 2), dim3(32, 8), 0, stream>>>(x, gamma, beta, stats, hnT);
  // qk8 = hnT * [wq;wk]^T (M=4096, N=1024, K=512), packed col bias, fp8 out
  gemm_abt<128, 2><<<dim3(8, 32, 2), dim3(256), 0, stream>>>(
      hnT, HS, 512, wb, 0, 512, 512, 1024, 1024, (ushort_t*)qk8, QS, qkbias, 2, 1.f,
      nullptr, nullptr, nullptr, 1, 2);
  // vC8 = wv * hnT^T (M=512, N=4096, K=512), row bias, fp8 out; UNR=2
  gemm_abt<64, 2><<<dim3(64, 4, 2), dim3(256), 0, stream>>>(
      wvb, 0, 512, hnT, HS, 512, 512, 4096, 4096, (ushort_t*)vC8, HS, bv, 1, 1.f,
      nullptr, nullptr, nullptr, 0, 2);
  // P' = exp(scale * q*k^T)/16 fp8 + PRIVATE rowsum partials (no atomics)
  // BM=256 MH=2, 8 waves: 1024 wg, 48KB LDS, acc 64 VGPR/lane
  gemm_qk<<<dim3(32, 16, 2), dim3(512), 0, stream>>>(
      qk8, QS, 1024, qk8 + 512, QS, 1024, 512, 4096, S8, SS, scale, lpart);
  // l[bz][m] = sum_bx lpart[bz][bx][m]
  rowsum_reduce<<<dim3(32), dim3(256), 0, stream>>>(lpart, l);
  // OT = P' * vC8^T (M=4096, N=512, K=4096), bf16 out
  gemm_pv<<<dim3(8, 16, 2), dim3(256), 0, stream>>>(
      S8, SS, 4096, vC8, HS, 4096, 4096, 512, OT, HS);
  // y = wo * (OT/l')^T + bo + x (M=512, N=4096, K=512), fp32 + residual; UNR=2
  gemm_abt<64, 2><<<dim3(64, 4, 2), dim3(256), 0, stream>>>(
      wob, 0, 512, OT, HS, 512, 512, 4096, 4096, nullptr, HS, bo, 1, 1.f,
      out, x, l, 0, 1);
}